// Round 9
// baseline (472.371 us; speedup 1.0000x reference)
//
#include <hip/hip_runtime.h>
#include <hip/hip_bf16.h>
#include <math.h>

#define B 8
#define N 10000
#define D 16
#define E 320000
#define EH 32
#define EOUT 30
#define NOUT 64
#define FEAT 35   // 2*D + 2 + 1
#define FILL_BLOCKS ((E + 255) / 256)      // 1250
#define PQ_BLOCKS   ((B * N * 64) / 256)   // 20000

// fast sigmoid: v_exp_f32 + v_rcp_f32 (no precise-division sequence)
__device__ __forceinline__ float sigmoidf_(float v) {
    return __builtin_amdgcn_rcpf(1.0f + __expf(-v));
}

__device__ __forceinline__ unsigned int pack_bf16_2(float a, float b) {
    unsigned ua = __float_as_uint(a), ub = __float_as_uint(b);
    ua = (ua + 0x7FFFu + ((ua >> 16) & 1u)) >> 16;
    ub = (ub + 0x7FFFu + ((ub >> 16) & 1u)) >> 16;
    return ua | (ub << 16);
}

__device__ __forceinline__ float bf16lo(unsigned v) { return __uint_as_float(v << 16); }
__device__ __forceinline__ float bf16hi(unsigned v) { return __uint_as_float(v & 0xFFFF0000u); }

// ---------------------------------------------------------------------------
// Fused: edge_attr column stats (mean/std ddof=1) + CSR degree counting
// ---------------------------------------------------------------------------
__global__ void stats_count_kernel(const float* __restrict__ ea,
                                   const int* __restrict__ eidx,
                                   float* __restrict__ stats,
                                   int* __restrict__ cnt) {
    float s0 = 0.f, s1 = 0.f, q0 = 0.f, q1 = 0.f;
    for (int i = blockIdx.x * blockDim.x + threadIdx.x; i < E; i += gridDim.x * blockDim.x) {
        float2 v = *(const float2*)(ea + 2 * (size_t)i);
        s0 += v.x; q0 += v.x * v.x;
        s1 += v.y; q1 += v.y * v.y;
        atomicAdd(&cnt[eidx[E + i]], 1);      // tgt (in)
        atomicAdd(&cnt[N + eidx[i]], 1);      // src (out)
    }
    #pragma unroll
    for (int off = 32; off > 0; off >>= 1) {
        s0 += __shfl_down(s0, off);
        s1 += __shfl_down(s1, off);
        q0 += __shfl_down(q0, off);
        q1 += __shfl_down(q1, off);
    }
    if ((threadIdx.x & 63) == 0) {
        atomicAdd(&stats[0], s0);
        atomicAdd(&stats[1], s1);
        atomicAdd(&stats[2], q0);
        atomicAdd(&stats[3], q1);
    }
}

// ---------------------------------------------------------------------------
// Scan (single block) + stats finalize on thread 0
// ---------------------------------------------------------------------------
__global__ void __launch_bounds__(1024) scan_kernel(const int* __restrict__ cnt_in,
                                                    int* __restrict__ offs,
                                                    int* __restrict__ cursor,
                                                    float* __restrict__ stats) {
    if (threadIdx.x == 0) {
        const float n = (float)E;
        float s0 = stats[0], s1 = stats[1], q0 = stats[2], q1 = stats[3];
        float v0 = (q0 - s0 * s0 / n) / (n - 1.0f);
        float v1 = (q1 - s1 * s1 / n) / (n - 1.0f);
        stats[4] = s0 / n;
        stats[5] = 1.0f / sqrtf(v0);
        stats[6] = s1 / n;
        stats[7] = 1.0f / sqrtf(v1);
    }
    const int M = 2 * N;
    const int CH = 20;
    __shared__ int lds[1024];
    int t = threadIdx.x;
    int base = t * CH;
    int loc[CH];
    int s = 0;
    #pragma unroll
    for (int i = 0; i < CH; i++) {
        int idx = base + i;
        int v = (idx < M) ? cnt_in[idx] : 0;
        loc[i] = s;
        s += v;
    }
    lds[t] = s;
    __syncthreads();
    for (int off = 1; off < 1024; off <<= 1) {
        int v = (t >= off) ? lds[t - off] : 0;
        __syncthreads();
        lds[t] += v;
        __syncthreads();
    }
    int tbase = (t > 0) ? lds[t - 1] : 0;
    #pragma unroll
    for (int i = 0; i < CH; i++) {
        int idx = base + i;
        if (idx < M) {
            offs[idx] = tbase + loc[i];
            cursor[idx] = tbase + loc[i];
        }
    }
    if (t == 1023) offs[M] = lds[1023];
}

// ---------------------------------------------------------------------------
// Fused fill (CSR lists) + P/Q/wind precompute. Block-range split.
// P[b,n,:] = x[b,n]@W1[0:16,:], Q[b,n,:] = x[b,n]@W1[16:32,:]+b1
// SW[b,n] = (speed, sdir) denormalized wind
// ---------------------------------------------------------------------------
__global__ void __launch_bounds__(256) fill_pq_kernel(
    const int* __restrict__ eidx, int* __restrict__ cursor,
    int* __restrict__ lists,
    const float* __restrict__ x, const float* __restrict__ W1,
    const float* __restrict__ b1,
    const float* __restrict__ wind_mean, const float* __restrict__ wind_std,
    float* __restrict__ P, float* __restrict__ Q, float2* __restrict__ SW)
{
    if (blockIdx.x < FILL_BLOCKS) {
        int e = blockIdx.x * 256 + threadIdx.x;
        if (e >= E) return;
        int p = atomicAdd(&cursor[eidx[E + e]], 1);
        lists[p] = e;
        int q = atomicAdd(&cursor[N + eidx[e]], 1);
        lists[q] = e;
    } else {
        int wid = ((blockIdx.x - FILL_BLOCKS) * 256 + threadIdx.x) >> 6;
        int lane = threadIdx.x & 63;
        if (wid >= B * N) return;
        int j = lane & 31;
        int half = lane >> 5;
        const float* xr = x + (size_t)wid * D;
        float acc = half ? b1[j] : 0.f;
        const float* Wb = W1 + (half ? D * EH : 0);
        #pragma unroll
        for (int d = 0; d < D; d++)
            acc = fmaf(xr[d], Wb[d * EH + j], acc);
        float* dst = half ? Q : P;
        dst[(size_t)wid * EH + j] = acc;
        if (lane == 0) {
            float2 xw = *(const float2*)(xr + 14);
            SW[wid] = make_float2(fmaf(xw.x, wind_std[0], wind_mean[0]),
                                  fmaf(xw.y, wind_std[1], wind_mean[1]));
        }
    }
}

// ---------------------------------------------------------------------------
// Edge MLP (factored layer 1). XCD-swizzled (bb = blockIdx&7): each XCD's L2
// caches one batch's P+Q slice. eBuf layout [e][bb][32] bf16 so a gather
// wave reads 512B contiguous per edge (no cache-line amplification).
// ---------------------------------------------------------------------------
__global__ void __launch_bounds__(256) edge_mlp_kernel(
    const int* __restrict__ eidx, const float* __restrict__ ea,
    const float* __restrict__ W1, const float* __restrict__ W2,
    const float* __restrict__ b2, const float* __restrict__ stats,
    const float* __restrict__ P, const float* __restrict__ Q,
    const float2* __restrict__ SW, unsigned short* __restrict__ eBuf)
{
    int bb = blockIdx.x & 7;
    int e  = (blockIdx.x >> 3) * 256 + threadIdx.x;   // E % 256 == 0

    int src = eidx[e];
    int tgt = eidx[E + e];

    const float4* Pr = (const float4*)(P + ((size_t)bb * N + src) * EH);
    const float4* Qr = (const float4*)(Q + ((size_t)bb * N + tgt) * EH);

    float h[EH];
    #pragma unroll
    for (int i = 0; i < 8; i++) {
        float4 p = Pr[i];
        float4 q = Qr[i];
        h[4 * i + 0] = p.x + q.x;
        h[4 * i + 1] = p.y + q.y;
        h[4 * i + 2] = p.z + q.z;
        h[4 * i + 3] = p.w + q.w;
    }

    float2 eav = *(const float2*)(ea + 2 * (size_t)e);
    float dist = eav.x, cdir = eav.y;
    float f32v = (dist - stats[4]) * stats[5];
    float f33v = (cdir - stats[6]) * stats[7];

    float2 sw = SW[(size_t)bb * N + src];
    float ew = fmaxf(3.0f * sw.x * __cosf(fabsf(cdir - sw.y)) *
                     __builtin_amdgcn_rcpf(dist), 0.0f);

    const float* W1r32 = W1 + 32 * EH;
    const float* W1r33 = W1 + 33 * EH;
    const float* W1r34 = W1 + 34 * EH;
    #pragma unroll
    for (int j = 0; j < EH; j++) {
        float v = h[j];
        v = fmaf(f32v, W1r32[j], v);
        v = fmaf(f33v, W1r33[j], v);
        v = fmaf(ew,   W1r34[j], v);
        h[j] = sigmoidf_(v);
    }

    float o[EOUT];
    #pragma unroll
    for (int j = 0; j < EOUT; j++) o[j] = b2[j];
    #pragma unroll
    for (int k = 0; k < EH; k++) {
        float hk = h[k];
        #pragma unroll
        for (int j = 0; j < EOUT; j++)
            o[j] = fmaf(hk, W2[k * EOUT + j], o[j]);
    }

    uint4 u[4];
    unsigned* uu = (unsigned*)u;
    #pragma unroll
    for (int i = 0; i < 15; i++)
        uu[i] = pack_bf16_2(sigmoidf_(o[2 * i]), sigmoidf_(o[2 * i + 1]));
    uu[15] = 0u;

    uint4* row = (uint4*)(eBuf + ((size_t)e * 8 + bb) * EH);   // [e][bb][32]
    #pragma unroll
    for (int i = 0; i < 4; i++) row[i] = u[i];
}

// ---------------------------------------------------------------------------
// Gather + node MLP. ONE WAVE PER NODE, all 8 batches at once.
// lane = bb*8 + c: per edge the wave loads 512B contiguous ([e][bb][32] bf16,
// lane's uint2 = 4 cols of batch bb). No cross-lane folds needed: every lane
// accumulates its 4 columns over all edges. lists read once per node.
// Node layer: 4.6KB LDS round-trip; lane (bb,c) computes outputs 8c..8c+7.
// ---------------------------------------------------------------------------
__global__ void __launch_bounds__(256) gather_kernel(
    const unsigned short* __restrict__ eBuf, const int* __restrict__ offs,
    const int* __restrict__ lists, const float* __restrict__ Wn,
    const float* __restrict__ bn, float* __restrict__ out)
{
    __shared__ float aggL[4][8][36];   // [wave][batch][32 cols + pad to 36]
    int wave = threadIdx.x >> 6;
    int lane = threadIdx.x & 63;
    int node = blockIdx.x * 4 + wave;          // grid = N/4 blocks
    int bb = lane >> 3;
    int c  = lane & 7;
    const uint2* ebase = (const uint2*)eBuf;   // edge e: 64 uint2 (8 bb x 8)

    float a0 = 0.f, a1 = 0.f, a2 = 0.f, a3 = 0.f;

    // in-list: add
    {
        int s = offs[node], e1 = offs[node + 1];
        int r = s;
        for (; r + 2 <= e1; r += 2) {
            int ei0 = __builtin_amdgcn_readfirstlane(lists[r]);
            int ei1 = __builtin_amdgcn_readfirstlane(lists[r + 1]);
            uint2 v0 = ebase[(size_t)ei0 * 64 + lane];
            uint2 v1 = ebase[(size_t)ei1 * 64 + lane];
            a0 += bf16lo(v0.x) + bf16lo(v1.x);
            a1 += bf16hi(v0.x) + bf16hi(v1.x);
            a2 += bf16lo(v0.y) + bf16lo(v1.y);
            a3 += bf16hi(v0.y) + bf16hi(v1.y);
        }
        if (r < e1) {
            int ei0 = __builtin_amdgcn_readfirstlane(lists[r]);
            uint2 v0 = ebase[(size_t)ei0 * 64 + lane];
            a0 += bf16lo(v0.x); a1 += bf16hi(v0.x);
            a2 += bf16lo(v0.y); a3 += bf16hi(v0.y);
        }
    }
    // out-list: subtract
    {
        int s = offs[N + node], e1 = offs[N + node + 1];
        int r = s;
        for (; r + 2 <= e1; r += 2) {
            int ei0 = __builtin_amdgcn_readfirstlane(lists[r]);
            int ei1 = __builtin_amdgcn_readfirstlane(lists[r + 1]);
            uint2 v0 = ebase[(size_t)ei0 * 64 + lane];
            uint2 v1 = ebase[(size_t)ei1 * 64 + lane];
            a0 -= bf16lo(v0.x) + bf16lo(v1.x);
            a1 -= bf16hi(v0.x) + bf16hi(v1.x);
            a2 -= bf16lo(v0.y) + bf16lo(v1.y);
            a3 -= bf16hi(v0.y) + bf16hi(v1.y);
        }
        if (r < e1) {
            int ei0 = __builtin_amdgcn_readfirstlane(lists[r]);
            uint2 v0 = ebase[(size_t)ei0 * 64 + lane];
            a0 -= bf16lo(v0.x); a1 -= bf16hi(v0.x);
            a2 -= bf16lo(v0.y); a3 -= bf16hi(v0.y);
        }
    }

    aggL[wave][bb][4 * c + 0] = a0;
    aggL[wave][bb][4 * c + 1] = a1;
    aggL[wave][bb][4 * c + 2] = a2;
    aggL[wave][bb][4 * c + 3] = a3;
    __syncthreads();

    // node layer: lane (bb,c) computes outputs j = 8c..8c+7 of (node, bb)
    float oacc[8];
    {
        const float4* bn4 = (const float4*)(bn + 8 * c);
        float4 b0 = bn4[0], b1v = bn4[1];
        oacc[0] = b0.x;  oacc[1] = b0.y;  oacc[2] = b0.z;  oacc[3] = b0.w;
        oacc[4] = b1v.x; oacc[5] = b1v.y; oacc[6] = b1v.z; oacc[7] = b1v.w;
    }
    #pragma unroll
    for (int k = 0; k < EOUT; k++) {
        float ak = aggL[wave][bb][k];
        const float4* w4 = (const float4*)(Wn + k * NOUT + 8 * c);
        float4 w0 = w4[0], w1 = w4[1];
        oacc[0] = fmaf(ak, w0.x, oacc[0]);
        oacc[1] = fmaf(ak, w0.y, oacc[1]);
        oacc[2] = fmaf(ak, w0.z, oacc[2]);
        oacc[3] = fmaf(ak, w0.w, oacc[3]);
        oacc[4] = fmaf(ak, w1.x, oacc[4]);
        oacc[5] = fmaf(ak, w1.y, oacc[5]);
        oacc[6] = fmaf(ak, w1.z, oacc[6]);
        oacc[7] = fmaf(ak, w1.w, oacc[7]);
    }
    float4 r0 = make_float4(sigmoidf_(oacc[0]), sigmoidf_(oacc[1]),
                            sigmoidf_(oacc[2]), sigmoidf_(oacc[3]));
    float4 r1 = make_float4(sigmoidf_(oacc[4]), sigmoidf_(oacc[5]),
                            sigmoidf_(oacc[6]), sigmoidf_(oacc[7]));
    float4* op = (float4*)(out + ((size_t)bb * N + node) * NOUT + 8 * c);
    op[0] = r0;
    op[1] = r1;
}

// ---------------------------------------------------------------------------
// Fallback (small ws): atomic path
// ---------------------------------------------------------------------------
__global__ void __launch_bounds__(256) edge_kernel_atomic(
    const float* __restrict__ x, const int* __restrict__ eidx,
    const float* __restrict__ ea,
    const float* __restrict__ wind_mean, const float* __restrict__ wind_std,
    const float* __restrict__ W1, const float* __restrict__ b1,
    const float* __restrict__ W2, const float* __restrict__ b2,
    const float* __restrict__ stats, float* __restrict__ agg)
{
    int t = blockIdx.x * blockDim.x + threadIdx.x;
    if (t >= B * E) return;
    int b = t / E;
    int e = t - b * E;
    int src = eidx[e];
    int tgt = eidx[E + e];
    const float* xs = x + ((size_t)b * N + src) * D;
    const float* xt = x + ((size_t)b * N + tgt) * D;
    float f[FEAT];
    #pragma unroll
    for (int i = 0; i < D; i++) f[i] = xs[i];
    #pragma unroll
    for (int i = 0; i < D; i++) f[D + i] = xt[i];
    float2 eav = *(const float2*)(ea + 2 * (size_t)e);
    f[32] = (eav.x - stats[4]) * stats[5];
    f[33] = (eav.y - stats[6]) * stats[7];
    float speed = f[14] * wind_std[0] + wind_mean[0];
    float sdir  = f[15] * wind_std[1] + wind_mean[1];
    f[34] = fmaxf(3.0f * speed * cosf(fabsf(eav.y - sdir)) / eav.x, 0.0f);
    float h[EH];
    #pragma unroll
    for (int j = 0; j < EH; j++) h[j] = b1[j];
    #pragma unroll
    for (int k = 0; k < FEAT; k++) {
        float fk = f[k];
        #pragma unroll
        for (int j = 0; j < EH; j++) h[j] = fmaf(fk, W1[k * EH + j], h[j]);
    }
    #pragma unroll
    for (int j = 0; j < EH; j++) h[j] = sigmoidf_(h[j]);
    float o[EOUT];
    #pragma unroll
    for (int j = 0; j < EOUT; j++) o[j] = b2[j];
    #pragma unroll
    for (int k = 0; k < EH; k++) {
        float hk = h[k];
        #pragma unroll
        for (int j = 0; j < EOUT; j++) o[j] = fmaf(hk, W2[k * EOUT + j], o[j]);
    }
    float* at = agg + ((size_t)b * N + tgt) * EOUT;
    float* as = agg + ((size_t)b * N + src) * EOUT;
    #pragma unroll
    for (int j = 0; j < EOUT; j++) {
        float v = sigmoidf_(o[j]);
        atomicAdd(at + j,  v);
        atomicAdd(as + j, -v);
    }
}

__global__ void __launch_bounds__(256) node_kernel_fallback(
    const float* __restrict__ agg, const float* __restrict__ Wn,
    const float* __restrict__ bn, float* __restrict__ out)
{
    int t = blockIdx.x * blockDim.x + threadIdx.x;
    if (t >= B * N * NOUT) return;
    int row = t >> 6;
    int j   = t & 63;
    const float* a = agg + (size_t)row * EOUT;
    float acc = bn[j];
    #pragma unroll
    for (int k = 0; k < EOUT; k++) acc = fmaf(a[k], Wn[k * NOUT + j], acc);
    out[t] = sigmoidf_(acc);
}

// ---------------------------------------------------------------------------
extern "C" void kernel_launch(void* const* d_in, const int* in_sizes, int n_in,
                              void* d_out, int out_size, void* d_ws, size_t ws_size,
                              hipStream_t stream) {
    const float* x         = (const float*)d_in[0];
    const int*   eidx      = (const int*)d_in[1];
    const float* ea        = (const float*)d_in[2];
    const float* wind_mean = (const float*)d_in[3];
    const float* wind_std  = (const float*)d_in[4];
    const float* W1        = (const float*)d_in[5];
    const float* b1        = (const float*)d_in[6];
    const float* W2        = (const float*)d_in[7];
    const float* b2        = (const float*)d_in[8];
    const float* Wn        = (const float*)d_in[9];
    const float* bn        = (const float*)d_in[10];
    float* out = (float*)d_out;

    char* ws = (char*)d_ws;
    // layout:
    //   stats [0,256) | offs [256,80384) | cnt/cursor [80384,160512)
    //   lists [160512,2720512)
    //   P [2720512,12960512) | Q [12960512,23200512)
    //   SW [23200512,23840512) | eBuf [23840512,...)
    float*          stats = (float*)(ws + 0);
    int*            offs  = (int*)(ws + 256);
    int*            cnt   = (int*)(ws + 80384);
    int*            lists = (int*)(ws + 160512);
    float*          P     = (float*)(ws + 2720512);
    float*          Q     = (float*)(ws + 12960512);
    float2*         SW    = (float2*)(ws + 23200512);
    unsigned short* eBuf  = (unsigned short*)(ws + 23840512);
    const size_t fixed = 23840512;
    const size_t eBufBytes = (size_t)B * E * EH * sizeof(unsigned short); // 163,840,000

    if (ws_size >= fixed + eBufBytes) {
        hipMemsetAsync(ws, 0, 160512, stream);

        stats_count_kernel<<<256, 256, 0, stream>>>(ea, eidx, stats, cnt);
        scan_kernel<<<1, 1024, 0, stream>>>(cnt, offs, cnt, stats);
        fill_pq_kernel<<<FILL_BLOCKS + PQ_BLOCKS, 256, 0, stream>>>(
            eidx, cnt, lists, x, W1, b1, wind_mean, wind_std, P, Q, SW);

        edge_mlp_kernel<<<(E / 256) * 8, 256, 0, stream>>>(
            eidx, ea, W1, W2, b2, stats, P, Q, SW, eBuf);
        gather_kernel<<<N / 4, 256, 0, stream>>>(
            eBuf, offs, lists, Wn, bn, out);
    } else {
        float* agg = (float*)(ws + 256);
        size_t zero_bytes = 256 + (size_t)B * N * EOUT * sizeof(float);
        hipMemsetAsync(ws, 0, zero_bytes, stream);
        stats_count_kernel<<<256, 256, 0, stream>>>(ea, eidx, stats, cnt);
        scan_kernel<<<1, 1024, 0, stream>>>(cnt, offs, cnt, stats);
        int nwork = B * E;
        edge_kernel_atomic<<<(nwork + 255) / 256, 256, 0, stream>>>(
            x, eidx, ea, wind_mean, wind_std, W1, b1, W2, b2, stats, agg);
        int nout_elems = B * N * NOUT;
        node_kernel_fallback<<<(nout_elems + 255) / 256, 256, 0, stream>>>(
            agg, Wn, bn, out);
    }
}